// Round 3
// baseline (724.990 us; speedup 1.0000x reference)
//
#include <hip/hip_runtime.h>
#include <stdint.h>
#include <stddef.h>

typedef __attribute__((ext_vector_type(8))) short bf16x8;
typedef __attribute__((ext_vector_type(4))) float f32x4;
typedef __attribute__((ext_vector_type(8))) unsigned short u16x8;
typedef __attribute__((ext_vector_type(4))) unsigned short u16x4;
typedef __attribute__((ext_vector_type(2))) unsigned short u16x2;

#define DEVINL __device__ __forceinline__

DEVINL unsigned short f2b(float x){
  union { float f; unsigned int u; } v; v.f = x;
  return (unsigned short)((v.u + 0x7FFFu + ((v.u >> 16) & 1u)) >> 16);
}
DEVINL float b2f(unsigned short h){
  union { float f; unsigned int u; } v; v.u = ((unsigned int)h) << 16;
  return v.f;
}

DEVINL void gl_lds16(void* g, void* lds){
  __builtin_amdgcn_global_load_lds(
      (__attribute__((address_space(1))) void*)g,
      (__attribute__((address_space(3))) void*)lds, 16, 0, 0);
}

// ---------------------------------------------------------------------------
// prep: transpose+cast weights to bf16 [n][k]; fold 1/16 into wq; fold BN.
// ---------------------------------------------------------------------------
__global__ __launch_bounds__(256) void prep_k(
    const float* __restrict__ m1w2, const float* __restrict__ m2w2,
    const float* __restrict__ wqp,  const float* __restrict__ wkp,
    const float* __restrict__ wvp,  const float* __restrict__ wop,
    const float* __restrict__ tdw,  const float* __restrict__ tdb,
    const float* __restrict__ bng,  const float* __restrict__ bnb,
    const float* __restrict__ bnm,  const float* __restrict__ bnv,
    unsigned short* __restrict__ wT, float* __restrict__ bns, float* __restrict__ bnt)
{
  int idx = blockIdx.x * 256 + threadIdx.x;
  if (idx < 786432){
    int mat = idx >> 17;
    int e   = idx & 131071;
    int i   = e >> 16;
    int eb  = e & 65535;
    int n = eb >> 8, kx = eb & 255;
    const float* src; float sc = 1.0f;
    if      (mat == 0) src = m1w2;
    else if (mat == 1) src = m2w2;
    else if (mat == 2){ src = wqp; sc = 0.0625f; }
    else if (mat == 3) src = wkp;
    else if (mat == 4) src = wvp;
    else               src = wop;
    wT[idx] = f2b(src[i*65536 + kx*256 + n] * sc);
  } else if (idx < 917504){
    int e = idx - 786432;
    int n = e >> 8, kx = e & 255;
    wT[786432 + e] = f2b(tdw[kx*512 + n]);
  } else if (idx < 918016){
    int c = idx - 917504;
    float s = bng[c] * rsqrtf(bnv[c] + 1e-5f);
    bns[c] = s;
    bnt[c] = (tdb[c] - bnm[c]) * s + bnb[c];
  }
}

// ---------------------------------------------------------------------------
// Generic GEMM (m97-style), used only for the final td+BN (N=512).
// ---------------------------------------------------------------------------
__global__ __launch_bounds__(256) void gemm_k(
    const unsigned short* __restrict__ A,
    const unsigned short* __restrict__ Wt,
    unsigned short* __restrict__ out,
    const float* __restrict__ bias,
    const unsigned short* __restrict__ addend,
    const float* __restrict__ bn_s,
    const float* __restrict__ bn_t,
    int ldc)
{
  __shared__ __attribute__((aligned(16))) unsigned short aT[512*8];
  __shared__ __attribute__((aligned(16))) unsigned short bT[512*8];
  __shared__ __attribute__((aligned(16))) unsigned short epi[128*140];

  const int tid  = threadIdx.x;
  const int lane = tid & 63;
  const int wave = tid >> 6;
  const int lrow = lane & 15, lq = lane >> 4;
  const int wr = wave >> 1, wc = wave & 1;
  const int m0 = blockIdx.x * 128;
  const int n0 = blockIdx.y * 128;

  f32x4 acc[4][4] = {};

  int aOff[4], bOff[4];
#pragma unroll
  for (int mt = 0; mt < 4; mt++){
    int row = wr*64 + mt*16 + lrow;
    aOff[mt] = row*64 + ((lq ^ ((row >> 1) & 3)) << 4);
  }
#pragma unroll
  for (int nt = 0; nt < 4; nt++){
    int row = wc*64 + nt*16 + lrow;
    bOff[nt] = row*64 + ((lq ^ ((row >> 1) & 3)) << 4);
  }

  const int s0 = tid, s1 = tid + 256;
  const int r0 = s0 >> 2, kc0 = (s0 & 3) ^ ((r0 >> 1) & 3);
  const int r1 = s1 >> 2, kc1 = (s1 & 3) ^ ((r1 >> 1) & 3);
  const unsigned short* Ab = A  + (size_t)m0 * 256;
  const unsigned short* Bb = Wt + (size_t)n0 * 256;
  char* aL = (char*)aT;
  char* bL = (char*)bT;
  const int wslot = wave * 64 * 16;

  for (int k0 = 0; k0 < 256; k0 += 32){
    __syncthreads();
    gl_lds16((void*)(Ab + r0*256 + k0 + kc0*8), aL + wslot);
    gl_lds16((void*)(Ab + r1*256 + k0 + kc1*8), aL + 4096 + wslot);
    gl_lds16((void*)(Bb + r0*256 + k0 + kc0*8), bL + wslot);
    gl_lds16((void*)(Bb + r1*256 + k0 + kc1*8), bL + 4096 + wslot);
    __syncthreads();
    bf16x8 af[4], bfr[4];
#pragma unroll
    for (int mt = 0; mt < 4; mt++) af[mt]  = *(const bf16x8*)(aL + aOff[mt]);
#pragma unroll
    for (int nt = 0; nt < 4; nt++) bfr[nt] = *(const bf16x8*)(bL + bOff[nt]);
#pragma unroll
    for (int mt = 0; mt < 4; mt++)
#pragma unroll
      for (int nt = 0; nt < 4; nt++)
        acc[mt][nt] = __builtin_amdgcn_mfma_f32_16x16x32_bf16(af[mt], bfr[nt], acc[mt][nt], 0, 0, 0);
  }

  __syncthreads();
#pragma unroll
  for (int mt = 0; mt < 4; mt++){
    int row = wr*64 + mt*16 + lq*4;
#pragma unroll
    for (int nt = 0; nt < 4; nt++){
      int col = wc*64 + nt*16 + lrow;
#pragma unroll
      for (int r = 0; r < 4; r++)
        epi[(row + r)*140 + col] = f2b(acc[mt][nt][r]);
    }
  }
  __syncthreads();

  const int erow = tid >> 1, h = tid & 1;
  const size_t gbase = (size_t)(m0 + erow) * (size_t)ldc + n0;
#pragma unroll
  for (int i = 0; i < 8; i++){
    int col = h*64 + i*8;
    u16x4 lo = *(const u16x4*)(&epi[erow*140 + col]);
    u16x4 hi = *(const u16x4*)(&epi[erow*140 + col + 4]);
    float y[8];
#pragma unroll
    for (int j = 0; j < 4; j++){ y[j] = b2f(lo[j]); y[4+j] = b2f(hi[j]); }
    if (addend){
      u16x8 ad = *(const u16x8*)(addend + gbase + col);
#pragma unroll
      for (int j = 0; j < 8; j++) y[j] += b2f(ad[j]);
    }
    if (bias){
#pragma unroll
      for (int j = 0; j < 8; j++) y[j] += bias[n0 + col + j];
    }
    if (bn_s){
#pragma unroll
      for (int j = 0; j < 8; j++){
        float t2 = y[j]*bn_s[n0 + col + j] + bn_t[n0 + col + j];
        y[j] = fmaxf(t2, 0.f);
      }
    }
    u16x8 o;
#pragma unroll
    for (int j = 0; j < 8; j++) o[j] = f2b(y[j]);
    *(u16x8*)(out + gbase + col) = o;
  }
}

// ---------------------------------------------------------------------------
// Per-WG 64x256x256 GEMM, BARRIER-FREE K-loop: B-fragments loaded straight
// from global (L2) into VGPRs in MFMA layout, prefetched 1 K-step ahead.
// A: LDS row-major [64][264] bf16 (read-only here). Wave w owns n-cols
// w*64..w*64+63; acc[4][4] covers all 64 rows.
// ---------------------------------------------------------------------------
DEVINL void wg_gemm_reg(const unsigned short* __restrict__ Wt,
                        const unsigned short* Als, int tid, f32x4 (&acc)[4][4])
{
  const int lane = tid & 63;
  const int wave = tid >> 6;
  const int lrow = lane & 15, lq = lane >> 4;
  const unsigned short* base[4];
#pragma unroll
  for (int nt = 0; nt < 4; nt++)
    base[nt] = Wt + (size_t)(wave*64 + nt*16 + lrow)*256 + lq*8;

  bf16x8 breg[2][4];
#pragma unroll
  for (int nt = 0; nt < 4; nt++) breg[0][nt] = *(const bf16x8*)(base[nt]);

#pragma unroll
  for (int k = 0; k < 8; k++){
    bf16x8 af[4];
#pragma unroll
    for (int mt = 0; mt < 4; mt++)
      af[mt] = *(const bf16x8*)(Als + (mt*16 + lrow)*264 + k*32 + lq*8);
    if (k < 7){
#pragma unroll
      for (int nt = 0; nt < 4; nt++)
        breg[(k+1)&1][nt] = *(const bf16x8*)(base[nt] + (k+1)*32);
    }
#pragma unroll
    for (int mt = 0; mt < 4; mt++)
#pragma unroll
      for (int nt = 0; nt < 4; nt++)
        acc[mt][nt] = __builtin_amdgcn_mfma_f32_16x16x32_bf16(af[mt], breg[k&1][nt], acc[mt][nt], 0, 0, 0);
  }
}

DEVINL void wg_epi(f32x4 (&acc)[4][4], unsigned short* Yls,
                   const unsigned short* resls, const float* __restrict__ bias, int tid)
{
  const int lane = tid & 63, wave = tid >> 6;
  const int lrow = lane & 15, lq = lane >> 4;
#pragma unroll
  for (int mt = 0; mt < 4; mt++){
#pragma unroll
    for (int nt = 0; nt < 4; nt++){
      int col = wave*64 + nt*16 + lrow;
#pragma unroll
      for (int r = 0; r < 4; r++){
        int row = mt*16 + lq*4 + r;
        float y = acc[mt][nt][r];
        if (bias) y += bias[col];
        if (resls) y += b2f(resls[row*264 + col]);
        Yls[row*264 + col] = f2b(y);
      }
    }
  }
  __syncthreads();
}

// v epilogue: write TRANSPOSED VT[col][row], stride 72 (16B-aligned rows).
DEVINL void wg_epi_vt(f32x4 (&acc)[4][4], unsigned short* VT, int tid)
{
  const int lane = tid & 63, wave = tid >> 6;
  const int lrow = lane & 15, lq = lane >> 4;
#pragma unroll
  for (int mt = 0; mt < 4; mt++){
#pragma unroll
    for (int nt = 0; nt < 4; nt++){
      int col = wave*64 + nt*16 + lrow;
      int row0 = mt*16 + lq*4;
      u16x4 w;
#pragma unroll
      for (int r = 0; r < 4; r++) w[r] = f2b(acc[mt][nt][r]);
      *(u16x4*)(VT + col*72 + row0) = w;
    }
  }
  __syncthreads();
}

// ---------------------------------------------------------------------------
// Fused transformer block: one WG per 64 rows, whole block in LDS.
// Buffers B0..B3 (64x264 bf16 = 33792 B each):
//   B0: fc -> q -> VT(spills 3K into B1, k dead) -> y
//   B1: H1 -> H2 -> k -> O
//   B2: h_pos (residual, v input)
//   B3: h_geo -> S/P
// ---------------------------------------------------------------------------
template<int CS, bool F32IN>
__global__ __launch_bounds__(256) void block_k(
    const float* __restrict__ pos,
    const float* __restrict__ featF,
    const unsigned short* __restrict__ featB,
    const float* __restrict__ w1a, const float* __restrict__ b1a,
    const float* __restrict__ w1b, const float* __restrict__ b1b,
    const unsigned short* __restrict__ m1w2T, const float* __restrict__ m1b2,
    const unsigned short* __restrict__ m2w2T, const float* __restrict__ m2b2,
    const unsigned short* __restrict__ wqT, const unsigned short* __restrict__ wkT,
    const unsigned short* __restrict__ wvT, const unsigned short* __restrict__ woT,
    const float* __restrict__ bo, const float* __restrict__ lgam,
    const float* __restrict__ lbet,
    unsigned short* __restrict__ out)
{
  __shared__ __attribute__((aligned(16))) char smem[135168];
  __shared__ float P3[64][3];
  __shared__ float Cg[4][3];
  __shared__ float Gg[64][4];
  __shared__ float sred[64][4];
  __shared__ float s2red[64][4];
  __shared__ float mub[64];
  __shared__ float rsb[64];

  unsigned short* B0 = (unsigned short*)(smem);
  unsigned short* B1 = (unsigned short*)(smem + 33792);
  unsigned short* B2 = (unsigned short*)(smem + 67584);
  unsigned short* B3 = (unsigned short*)(smem + 101376);
  constexpr int SS = (CS == 64) ? 66 : 18;
  constexpr int PS = (CS == 64) ? 72 : 40;
  float* Sb = (float*)B3;
  unsigned short* Pb = (unsigned short*)((char*)B3 + 64*SS*4);
  unsigned short* VT = B0;   // [256][72] bf16, spills 3072 B into B1 (dead k)

  const int tid  = threadIdx.x;
  const int lane = tid & 63;
  const int wave = tid >> 6;
  const int lrow = lane & 15, lq = lane >> 4;
  const int m0 = blockIdx.x * 64;

  // ---- load pos + fc(B0) ----
  if (tid < 64){
    P3[tid][0] = pos[(size_t)(m0+tid)*3 + 0];
    P3[tid][1] = pos[(size_t)(m0+tid)*3 + 1];
    P3[tid][2] = pos[(size_t)(m0+tid)*3 + 2];
  }
  {
    const int row = tid >> 2, cb = (tid & 3) * 64;
    if (F32IN){
      const float* src = featF + (size_t)(m0 + row)*256 + cb;
#pragma unroll
      for (int i = 0; i < 8; i++){
        float4 a = *(const float4*)(src + i*8);
        float4 b = *(const float4*)(src + i*8 + 4);
        u16x8 o;
        o[0]=f2b(a.x); o[1]=f2b(a.y); o[2]=f2b(a.z); o[3]=f2b(a.w);
        o[4]=f2b(b.x); o[5]=f2b(b.y); o[6]=f2b(b.z); o[7]=f2b(b.w);
        *(u16x8*)(B0 + row*264 + cb + i*8) = o;
      }
    } else {
      const unsigned short* src = featB + (size_t)(m0 + row)*256 + cb;
#pragma unroll
      for (int i = 0; i < 8; i++)
        *(u16x8*)(B0 + row*264 + cb + i*8) = *(const u16x8*)(src + i*8);
    }
  }
  __syncthreads();

  // ---- geometry ----
  constexpr int NCH = 64 / CS;
  if (tid < NCH*3){
    int ch = tid / 3, c = tid - ch*3;
    float s = 0.f;
    for (int r = 0; r < CS; r++) s += P3[ch*CS + r][c];
    Cg[ch][c] = s / (float)CS;
  }
  __syncthreads();
  if (tid < 64){
    int ch = (CS == 16) ? (tid >> 4) : 0;
    float x = P3[tid][0] - Cg[ch][0];
    float y = P3[tid][1] - Cg[ch][1];
    float z = P3[tid][2] - Cg[ch][2];
    Gg[tid][0] = x; Gg[tid][1] = y; Gg[tid][2] = z;
    Gg[tid][3] = sqrtf(x*x + y*y + z*z);
  }
  __syncthreads();

  // ---- H1 = relu(G @ w1a + b1a) -> B1 ----
  {
    const int c = tid;
    const float wa0 = w1a[c], wa1 = w1a[256+c], wa2 = w1a[512+c], wa3 = w1a[768+c];
    const float ba  = b1a[c];
    for (int r = 0; r < 64; r++){
      float v1 = ba + Gg[r][0]*wa0 + Gg[r][1]*wa1 + Gg[r][2]*wa2 + Gg[r][3]*wa3;
      B1[r*264 + c] = f2b(fmaxf(v1, 0.f));
    }
  }
  __syncthreads();
  // h_pos = fc + H1 @ m1w2 + b -> B2
  {
    f32x4 acc[4][4] = {};
    wg_gemm_reg(m1w2T, B1, tid, acc);
    wg_epi(acc, B2, B0, m1b2, tid);
  }
  // ---- H2 = relu(G @ w1b + b1b) -> B1 ----  (avg branch == 0 exactly)
  {
    const int c = tid;
    const float wb0 = w1b[768+c], wb1 = w1b[1024+c], wb2 = w1b[1280+c];
    const float bb  = b1b[c];
    for (int r = 0; r < 64; r++){
      float v2 = bb + Gg[r][0]*wb0 + Gg[r][1]*wb1 + Gg[r][2]*wb2;
      B1[r*264 + c] = f2b(fmaxf(v2, 0.f));
    }
  }
  __syncthreads();
  // h_geo = fc + H2 @ m2w2 + b -> B3
  {
    f32x4 acc[4][4] = {};
    wg_gemm_reg(m2w2T, B1, tid, acc);
    wg_epi(acc, B3, B0, m2b2, tid);
  }
  // q = h_geo @ wq(/16) -> B0 (fc dead) ; k = h_geo @ wk -> B1
  {
    f32x4 acc[4][4] = {};
    wg_gemm_reg(wqT, B3, tid, acc);
    wg_epi(acc, B0, nullptr, nullptr, tid);
  }
  {
    f32x4 acc[4][4] = {};
    wg_gemm_reg(wkT, B3, tid, acc);
    wg_epi(acc, B1, nullptr, nullptr, tid);
  }

  // ---- S = q k^T -> Sb (B3; h_geo dead) ----
  {
    constexpr int NT = CS / 16;
    f32x4 sacc[NT] = {};
    const int qrow = wave*16 + lrow;
#pragma unroll
    for (int kk = 0; kk < 8; kk++){
      bf16x8 aq = *(const bf16x8*)(B0 + qrow*264 + kk*32 + lq*8);
#pragma unroll
      for (int nt = 0; nt < NT; nt++){
        int brow = (CS == 64) ? (nt*16 + lrow) : (wave*16 + lrow);
        bf16x8 bk = *(const bf16x8*)(B1 + brow*264 + kk*32 + lq*8);
        sacc[nt] = __builtin_amdgcn_mfma_f32_16x16x32_bf16(aq, bk, sacc[nt], 0, 0, 0);
      }
    }
#pragma unroll
    for (int nt = 0; nt < NT; nt++){
#pragma unroll
      for (int r = 0; r < 4; r++){
        int srow = wave*16 + lq*4 + r;
        int scol = nt*16 + lrow;
        Sb[srow*SS + scol] = sacc[nt][r];
      }
    }
  }
  __syncthreads();

  // ---- softmax -> Pb (bf16) ----
  if (tid < 64){
    float mx = -3.0e38f;
    for (int j = 0; j < CS; j++) mx = fmaxf(mx, Sb[tid*SS + j]);
    float sum = 0.f;
    for (int j = 0; j < CS; j++){
      float e = __expf(Sb[tid*SS + j] - mx);
      Sb[tid*SS + j] = e; sum += e;
    }
    float inv = 1.0f / sum;
    for (int j = 0; j < CS; j++) Pb[tid*PS + j] = f2b(Sb[tid*SS + j] * inv);
    if (CS == 16){
      for (int j = 16; j < 32; j++) Pb[tid*PS + j] = 0;
    }
  }
  __syncthreads();

  // ---- v = h_pos @ wv -> VT (transposed, over B0; q dead, k-head clobbered)
  {
    f32x4 acc[4][4] = {};
    wg_gemm_reg(wvT, B2, tid, acc);
    wg_epi_vt(acc, VT, tid);
  }

  // ---- O = P @ V -> B1 ----
  {
    f32x4 oacc[4][4] = {};
    const int dbase = wave * 64;
    if (CS == 64){
#pragma unroll
      for (int kk = 0; kk < 2; kk++){
        bf16x8 ap[4];
#pragma unroll
        for (int mt = 0; mt < 4; mt++)
          ap[mt] = *(const bf16x8*)(Pb + (mt*16 + lrow)*PS + kk*32 + lq*8);
#pragma unroll
        for (int nt = 0; nt < 4; nt++){
          const int d = dbase + nt*16 + lrow;
          bf16x8 bv = *(const bf16x8*)(VT + d*72 + kk*32 + lq*8);
#pragma unroll
          for (int mt = 0; mt < 4; mt++)
            oacc[mt][nt] = __builtin_amdgcn_mfma_f32_16x16x32_bf16(ap[mt], bv, oacc[mt][nt], 0, 0, 0);
        }
      }
    } else {
#pragma unroll
      for (int mt = 0; mt < 4; mt++){
        bf16x8 ap = *(const bf16x8*)(Pb + (mt*16 + lrow)*PS + lq*8);
#pragma unroll
        for (int nt = 0; nt < 4; nt++){
          const int d = dbase + nt*16 + lrow;
          bf16x8 bv = *(const bf16x8*)(VT + d*72 + mt*16 + (lq & 1)*8);
          oacc[mt][nt] = __builtin_amdgcn_mfma_f32_16x16x32_bf16(ap, bv, oacc[mt][nt], 0, 0, 0);
        }
      }
    }
    __syncthreads();   // all VT reads done before O overwrites B1 (VT spill)
#pragma unroll
    for (int mt = 0; mt < 4; mt++){
#pragma unroll
      for (int nt = 0; nt < 4; nt++){
#pragma unroll
        for (int r = 0; r < 4; r++){
          int row = mt*16 + lq*4 + r;
          int col = dbase + nt*16 + lrow;
          B1[row*264 + col] = f2b(oacc[mt][nt][r]);
        }
      }
    }
  }
  __syncthreads();

  // ---- y = O @ wo -> B0 ; then LN(y + bo + h_pos) -> out ----
  {
    f32x4 acc[4][4] = {};
    wg_gemm_reg(woT, B1, tid, acc);
    wg_epi(acc, B0, nullptr, nullptr, tid);
  }
  {
    const int row = tid >> 2, part = tid & 3;
    const size_t gr = (size_t)(m0 + row) * 256;
    float sm = 0.f, sq = 0.f;
#pragma unroll
    for (int i = 0; i < 8; i++){
      int col = part*64 + i*8;
      u16x8 v  = *(const u16x8*)(B0 + row*264 + col);
      u16x8 rr = *(const u16x8*)(B2 + row*264 + col);
      u16x8 w;
#pragma unroll
      for (int j = 0; j < 8; j++){
        float y = b2f(v[j]) + bo[col + j] + b2f(rr[j]);
        sm += y; sq += y*y;
        w[j] = f2b(y);
      }
      *(u16x8*)(B0 + row*264 + col) = w;
    }
    sred[row][part] = sm; s2red[row][part] = sq;
    __syncthreads();
    if (tid < 64){
      float s  = sred[tid][0] + sred[tid][1] + sred[tid][2] + sred[tid][3];
      float q2 = s2red[tid][0] + s2red[tid][1] + s2red[tid][2] + s2red[tid][3];
      float mu = s * (1.0f/256.0f);
      float var = q2 * (1.0f/256.0f) - mu*mu;
      mub[tid] = mu;
      rsb[tid] = rsqrtf(var + 1e-5f);
    }
    __syncthreads();
    const float mu = mub[row], rs = rsb[row];
#pragma unroll
    for (int i = 0; i < 8; i++){
      int col = part*64 + i*8;
      u16x8 v = *(const u16x8*)(B0 + row*264 + col);
      u16x8 o;
#pragma unroll
      for (int j = 0; j < 8; j++)
        o[j] = f2b((b2f(v[j]) - mu)*rs*lgam[col + j] + lbet[col + j]);
      *(u16x8*)(out + gr + col) = o;
    }
  }
}

// ---------------------------------------------------------------------------
// Output: pos_ds gather + KNN max-pool.
// ---------------------------------------------------------------------------
__global__ __launch_bounds__(256) void out_k(
    const unsigned short* __restrict__ F2,
    const float* __restrict__ pos,
    const int* __restrict__ fps,
    const int* __restrict__ knn,
    float* __restrict__ outp)
{
  const int p = blockIdx.x;
  const int b = p >> 11;
  const int t = threadIdx.x;
  const int* kn = knn + (size_t)p * 16;
  const int c = t * 2;
  float m1 = -3.0e38f, m2 = -3.0e38f;
  for (int j = 0; j < 16; j++){
    int idx = kn[j];
    size_t row = ((size_t)b * 8192 + idx) * 512;
    u16x2 v = *(const u16x2*)(F2 + row + c);
    m1 = fmaxf(m1, b2f(v.x));
    m2 = fmaxf(m2, b2f(v.y));
  }
  float* of = outp + 49152 + (size_t)p * 512 + c;
  float2 o; o.x = m1; o.y = m2;
  *(float2*)of = o;
  if (t < 3){
    int fi = fps[p];
    outp[(size_t)p*3 + t] = pos[((size_t)b*8192 + fi)*3 + t];
  }
}

// ---------------------------------------------------------------------------
extern "C" void kernel_launch(void* const* d_in, const int* in_sizes, int n_in,
                              void* d_out, int out_size, void* d_ws, size_t ws_size,
                              hipStream_t stream)
{
  (void)in_sizes; (void)n_in; (void)out_size; (void)ws_size;

  const float* pos  = (const float*)d_in[0];
  const float* feat = (const float*)d_in[1];
  const int*   fps  = (const int*)d_in[2];
  const int*   knn  = (const int*)d_in[3];
  const float* m1w1 = (const float*)d_in[6];
  const float* m1b1 = (const float*)d_in[7];
  const float* m1w2 = (const float*)d_in[8];
  const float* m1b2 = (const float*)d_in[9];
  const float* m2w1 = (const float*)d_in[10];
  const float* m2b1 = (const float*)d_in[11];
  const float* m2w2 = (const float*)d_in[12];
  const float* m2b2 = (const float*)d_in[13];
  const float* wq   = (const float*)d_in[14];
  const float* wk   = (const float*)d_in[15];
  const float* wv   = (const float*)d_in[16];
  const float* wo   = (const float*)d_in[17];
  const float* bo   = (const float*)d_in[18];
  const float* lng  = (const float*)d_in[19];
  const float* lnb  = (const float*)d_in[20];
  const float* tdw  = (const float*)d_in[21];
  const float* tdb  = (const float*)d_in[22];
  const float* bng  = (const float*)d_in[23];
  const float* bnb  = (const float*)d_in[24];
  const float* bnm  = (const float*)d_in[25];
  const float* bnv  = (const float*)d_in[26];

  char* ws = (char*)d_ws;
  unsigned short* wT = (unsigned short*)ws;
  float* bns = (float*)(ws + 1835008);
  float* bnt = (float*)(ws + 1837056);
  const size_t SLOT = 33554432;
  unsigned short* A  = (unsigned short*)(ws + 2097152);
  unsigned short* Bs = (unsigned short*)(ws + 2097152 + SLOT);
  unsigned short* E  = (unsigned short*)(ws + 2097152 + 2*SLOT);

  auto wtm = [&](int mat, int i){ return wT + (size_t)mat*131072 + (size_t)i*65536; };
  unsigned short* tdT = wT + 786432;

  prep_k<<<3586, 256, 0, stream>>>(m1w2, m2w2, wq, wk, wv, wo, tdw, tdb, bng, bnb, bnm, bnv,
                                   wT, bns, bnt);

  block_k<16, true><<<1024, 256, 0, stream>>>(
      pos, feat, nullptr,
      m1w1, m1b1, m2w1, m2b1,
      wtm(0,0), m1b2, wtm(1,0), m2b2,
      wtm(2,0), wtm(3,0), wtm(4,0), wtm(5,0),
      bo, lng, lnb, A);

  block_k<64, false><<<1024, 256, 0, stream>>>(
      pos, nullptr, A,
      m1w1 + 1024, m1b1 + 256, m2w1 + 1536, m2b1 + 256,
      wtm(0,1), m1b2 + 256, wtm(1,1), m2b2 + 256,
      wtm(2,1), wtm(3,1), wtm(4,1), wtm(5,1),
      bo + 256, lng + 256, lnb + 256, Bs);

  gemm_k<<<dim3(512,4), 256, 0, stream>>>(Bs, tdT, E, nullptr, nullptr, bns, bnt, 512);

  out_k<<<16384, 256, 0, stream>>>(E, pos, fps, knn, (float*)d_out);
}

// Round 4
// 624.356 us; speedup vs baseline: 1.1612x; 1.1612x over previous
//
#include <hip/hip_runtime.h>
#include <stdint.h>
#include <stddef.h>

typedef __attribute__((ext_vector_type(8))) short bf16x8;
typedef __attribute__((ext_vector_type(4))) float f32x4;
typedef __attribute__((ext_vector_type(8))) unsigned short u16x8;
typedef __attribute__((ext_vector_type(4))) unsigned short u16x4;
typedef __attribute__((ext_vector_type(2))) unsigned short u16x2;

#define DEVINL __device__ __forceinline__

DEVINL unsigned short f2b(float x){
  union { float f; unsigned int u; } v; v.f = x;
  return (unsigned short)((v.u + 0x7FFFu + ((v.u >> 16) & 1u)) >> 16);
}
DEVINL float b2f(unsigned short h){
  union { float f; unsigned int u; } v; v.u = ((unsigned int)h) << 16;
  return v.f;
}

DEVINL void gl_lds16(void* g, void* lds){
  __builtin_amdgcn_global_load_lds(
      (__attribute__((address_space(1))) void*)g,
      (__attribute__((address_space(3))) void*)lds, 16, 0, 0);
}

// ---------------------------------------------------------------------------
// prep: transpose+cast weights to bf16 [n][k]; fold 1/16 into wq; fold BN.
// ---------------------------------------------------------------------------
__global__ __launch_bounds__(256) void prep_k(
    const float* __restrict__ m1w2, const float* __restrict__ m2w2,
    const float* __restrict__ wqp,  const float* __restrict__ wkp,
    const float* __restrict__ wvp,  const float* __restrict__ wop,
    const float* __restrict__ tdw,  const float* __restrict__ tdb,
    const float* __restrict__ bng,  const float* __restrict__ bnb,
    const float* __restrict__ bnm,  const float* __restrict__ bnv,
    unsigned short* __restrict__ wT, float* __restrict__ bns, float* __restrict__ bnt)
{
  int idx = blockIdx.x * 256 + threadIdx.x;
  if (idx < 786432){
    int mat = idx >> 17;
    int e   = idx & 131071;
    int i   = e >> 16;
    int eb  = e & 65535;
    int n = eb >> 8, kx = eb & 255;
    const float* src; float sc = 1.0f;
    if      (mat == 0) src = m1w2;
    else if (mat == 1) src = m2w2;
    else if (mat == 2){ src = wqp; sc = 0.0625f; }
    else if (mat == 3) src = wkp;
    else if (mat == 4) src = wvp;
    else               src = wop;
    wT[idx] = f2b(src[i*65536 + kx*256 + n] * sc);
  } else if (idx < 917504){
    int e = idx - 786432;
    int n = e >> 8, kx = e & 255;
    wT[786432 + e] = f2b(tdw[kx*512 + n]);
  } else if (idx < 918016){
    int c = idx - 917504;
    float s = bng[c] * rsqrtf(bnv[c] + 1e-5f);
    bns[c] = s;
    bnt[c] = (tdb[c] - bnm[c]) * s + bnb[c];
  }
}

// ---------------------------------------------------------------------------
// Generic GEMM (m97-style), used only for the final td+BN (N=512).
// ---------------------------------------------------------------------------
__global__ __launch_bounds__(256) void gemm_k(
    const unsigned short* __restrict__ A,
    const unsigned short* __restrict__ Wt,
    unsigned short* __restrict__ out,
    const float* __restrict__ bias,
    const unsigned short* __restrict__ addend,
    const float* __restrict__ bn_s,
    const float* __restrict__ bn_t,
    int ldc)
{
  __shared__ __attribute__((aligned(16))) unsigned short aT[512*8];
  __shared__ __attribute__((aligned(16))) unsigned short bT[512*8];
  __shared__ __attribute__((aligned(16))) unsigned short epi[128*140];

  const int tid  = threadIdx.x;
  const int lane = tid & 63;
  const int wave = tid >> 6;
  const int lrow = lane & 15, lq = lane >> 4;
  const int wr = wave >> 1, wc = wave & 1;
  const int m0 = blockIdx.x * 128;
  const int n0 = blockIdx.y * 128;

  f32x4 acc[4][4] = {};

  int aOff[4], bOff[4];
#pragma unroll
  for (int mt = 0; mt < 4; mt++){
    int row = wr*64 + mt*16 + lrow;
    aOff[mt] = row*64 + ((lq ^ ((row >> 1) & 3)) << 4);
  }
#pragma unroll
  for (int nt = 0; nt < 4; nt++){
    int row = wc*64 + nt*16 + lrow;
    bOff[nt] = row*64 + ((lq ^ ((row >> 1) & 3)) << 4);
  }

  const int s0 = tid, s1 = tid + 256;
  const int r0 = s0 >> 2, kc0 = (s0 & 3) ^ ((r0 >> 1) & 3);
  const int r1 = s1 >> 2, kc1 = (s1 & 3) ^ ((r1 >> 1) & 3);
  const unsigned short* Ab = A  + (size_t)m0 * 256;
  const unsigned short* Bb = Wt + (size_t)n0 * 256;
  char* aL = (char*)aT;
  char* bL = (char*)bT;
  const int wslot = wave * 64 * 16;

  for (int k0 = 0; k0 < 256; k0 += 32){
    __syncthreads();
    gl_lds16((void*)(Ab + r0*256 + k0 + kc0*8), aL + wslot);
    gl_lds16((void*)(Ab + r1*256 + k0 + kc1*8), aL + 4096 + wslot);
    gl_lds16((void*)(Bb + r0*256 + k0 + kc0*8), bL + wslot);
    gl_lds16((void*)(Bb + r1*256 + k0 + kc1*8), bL + 4096 + wslot);
    __syncthreads();
    bf16x8 af[4], bfr[4];
#pragma unroll
    for (int mt = 0; mt < 4; mt++) af[mt]  = *(const bf16x8*)(aL + aOff[mt]);
#pragma unroll
    for (int nt = 0; nt < 4; nt++) bfr[nt] = *(const bf16x8*)(bL + bOff[nt]);
#pragma unroll
    for (int mt = 0; mt < 4; mt++)
#pragma unroll
      for (int nt = 0; nt < 4; nt++)
        acc[mt][nt] = __builtin_amdgcn_mfma_f32_16x16x32_bf16(af[mt], bfr[nt], acc[mt][nt], 0, 0, 0);
  }

  __syncthreads();
#pragma unroll
  for (int mt = 0; mt < 4; mt++){
    int row = wr*64 + mt*16 + lq*4;
#pragma unroll
    for (int nt = 0; nt < 4; nt++){
      int col = wc*64 + nt*16 + lrow;
#pragma unroll
      for (int r = 0; r < 4; r++)
        epi[(row + r)*140 + col] = f2b(acc[mt][nt][r]);
    }
  }
  __syncthreads();

  const int erow = tid >> 1, h = tid & 1;
  const size_t gbase = (size_t)(m0 + erow) * (size_t)ldc + n0;
#pragma unroll
  for (int i = 0; i < 8; i++){
    int col = h*64 + i*8;
    u16x4 lo = *(const u16x4*)(&epi[erow*140 + col]);
    u16x4 hi = *(const u16x4*)(&epi[erow*140 + col + 4]);
    float y[8];
#pragma unroll
    for (int j = 0; j < 4; j++){ y[j] = b2f(lo[j]); y[4+j] = b2f(hi[j]); }
    if (addend){
      u16x8 ad = *(const u16x8*)(addend + gbase + col);
#pragma unroll
      for (int j = 0; j < 8; j++) y[j] += b2f(ad[j]);
    }
    if (bias){
#pragma unroll
      for (int j = 0; j < 8; j++) y[j] += bias[n0 + col + j];
    }
    if (bn_s){
#pragma unroll
      for (int j = 0; j < 8; j++){
        float t2 = y[j]*bn_s[n0 + col + j] + bn_t[n0 + col + j];
        y[j] = fmaxf(t2, 0.f);
      }
    }
    u16x8 o;
#pragma unroll
    for (int j = 0; j < 8; j++) o[j] = f2b(y[j]);
    *(u16x8*)(out + gbase + col) = o;
  }
}

// ---------------------------------------------------------------------------
// Per-WG 64x256x256 GEMM, 8 waves (512 thr): wave w owns n-cols w*32..+31
// (mt=4, nt=2). ALL 16 B-fragments prefetched from L2 into VGPRs up front,
// barrier-free K-loop. A read from LDS [64][264].
// ---------------------------------------------------------------------------
DEVINL void wg_gemm_reg(const unsigned short* __restrict__ Wt,
                        const unsigned short* Als, int tid, f32x4 (&acc)[4][2])
{
  const int lane = tid & 63;
  const int wave = tid >> 6;          // 0..7
  const int lrow = lane & 15, lq = lane >> 4;
  const unsigned short* base[2];
#pragma unroll
  for (int nt = 0; nt < 2; nt++)
    base[nt] = Wt + (size_t)(wave*32 + nt*16 + lrow)*256 + lq*8;

  bf16x8 breg[8][2];
#pragma unroll
  for (int k = 0; k < 8; k++)
#pragma unroll
    for (int nt = 0; nt < 2; nt++)
      breg[k][nt] = *(const bf16x8*)(base[nt] + k*32);

#pragma unroll
  for (int k = 0; k < 8; k++){
    bf16x8 af[4];
#pragma unroll
    for (int mt = 0; mt < 4; mt++)
      af[mt] = *(const bf16x8*)(Als + (mt*16 + lrow)*264 + k*32 + lq*8);
#pragma unroll
    for (int mt = 0; mt < 4; mt++)
#pragma unroll
      for (int nt = 0; nt < 2; nt++)
        acc[mt][nt] = __builtin_amdgcn_mfma_f32_16x16x32_bf16(af[mt], breg[k][nt], acc[mt][nt], 0, 0, 0);
  }
}

DEVINL void wg_epi(f32x4 (&acc)[4][2], unsigned short* Yls,
                   const unsigned short* resls, const float* __restrict__ bias, int tid)
{
  const int lane = tid & 63, wave = tid >> 6;
  const int lrow = lane & 15, lq = lane >> 4;
#pragma unroll
  for (int mt = 0; mt < 4; mt++){
#pragma unroll
    for (int nt = 0; nt < 2; nt++){
      int col = wave*32 + nt*16 + lrow;
#pragma unroll
      for (int r = 0; r < 4; r++){
        int row = mt*16 + lq*4 + r;
        float y = acc[mt][nt][r];
        if (bias) y += bias[col];
        if (resls) y += b2f(resls[row*264 + col]);
        Yls[row*264 + col] = f2b(y);
      }
    }
  }
  __syncthreads();
}

// v epilogue: write TRANSPOSED VT[col][row], stride 72 (16B-aligned rows).
DEVINL void wg_epi_vt(f32x4 (&acc)[4][2], unsigned short* VT, int tid)
{
  const int lane = tid & 63, wave = tid >> 6;
  const int lrow = lane & 15, lq = lane >> 4;
#pragma unroll
  for (int mt = 0; mt < 4; mt++){
#pragma unroll
    for (int nt = 0; nt < 2; nt++){
      int col = wave*32 + nt*16 + lrow;
      int row0 = mt*16 + lq*4;
      u16x4 w;
#pragma unroll
      for (int r = 0; r < 4; r++) w[r] = f2b(acc[mt][nt][r]);
      *(u16x4*)(VT + col*72 + row0) = w;
    }
  }
  __syncthreads();
}

// ---------------------------------------------------------------------------
// Fused transformer block: one WG (512 thr, 8 waves) per 64 rows.
// Buffers B0..B3 (64x264 bf16 = 33792 B each):
//   B0: fc -> q -> VT(spills 3K into B1) -> y
//   B1: H1 -> H2 -> k -> O
//   B2: h_pos (residual, v input)
//   B3: h_geo -> S/P
// ---------------------------------------------------------------------------
template<int CS, bool F32IN>
__global__ __launch_bounds__(512, 2) void block_k(
    const float* __restrict__ pos,
    const float* __restrict__ featF,
    const unsigned short* __restrict__ featB,
    const float* __restrict__ w1a, const float* __restrict__ b1a,
    const float* __restrict__ w1b, const float* __restrict__ b1b,
    const unsigned short* __restrict__ m1w2T, const float* __restrict__ m1b2,
    const unsigned short* __restrict__ m2w2T, const float* __restrict__ m2b2,
    const unsigned short* __restrict__ wqT, const unsigned short* __restrict__ wkT,
    const unsigned short* __restrict__ wvT, const unsigned short* __restrict__ woT,
    const float* __restrict__ bo, const float* __restrict__ lgam,
    const float* __restrict__ lbet,
    unsigned short* __restrict__ out)
{
  __shared__ __attribute__((aligned(16))) char smem[135168];
  __shared__ float P3[64][3];
  __shared__ float Cg[4][3];
  __shared__ float Gg[64][4];
  __shared__ float sred[64][8];
  __shared__ float s2red[64][8];
  __shared__ float mub[64];
  __shared__ float rsb[64];

  unsigned short* B0 = (unsigned short*)(smem);
  unsigned short* B1 = (unsigned short*)(smem + 33792);
  unsigned short* B2 = (unsigned short*)(smem + 67584);
  unsigned short* B3 = (unsigned short*)(smem + 101376);
  constexpr int SS = (CS == 64) ? 66 : 18;
  constexpr int PS = (CS == 64) ? 72 : 40;
  float* Sb = (float*)B3;
  unsigned short* Pb = (unsigned short*)((char*)B3 + 64*SS*4);
  unsigned short* VT = B0;   // [256][72] bf16, spills 3072 B into B1 (dead k)

  const int tid  = threadIdx.x;
  const int lane = tid & 63;
  const int wave = tid >> 6;          // 0..7
  const int lrow = lane & 15, lq = lane >> 4;
  const int m0 = blockIdx.x * 64;

  // ---- load pos + fc(B0) ----
  if (tid < 64){
    P3[tid][0] = pos[(size_t)(m0+tid)*3 + 0];
    P3[tid][1] = pos[(size_t)(m0+tid)*3 + 1];
    P3[tid][2] = pos[(size_t)(m0+tid)*3 + 2];
  }
  {
    const int row = tid >> 3, cb = (tid & 7) * 32;
    if (F32IN){
      const float* src = featF + (size_t)(m0 + row)*256 + cb;
#pragma unroll
      for (int i = 0; i < 4; i++){
        float4 a = *(const float4*)(src + i*8);
        float4 b = *(const float4*)(src + i*8 + 4);
        u16x8 o;
        o[0]=f2b(a.x); o[1]=f2b(a.y); o[2]=f2b(a.z); o[3]=f2b(a.w);
        o[4]=f2b(b.x); o[5]=f2b(b.y); o[6]=f2b(b.z); o[7]=f2b(b.w);
        *(u16x8*)(B0 + row*264 + cb + i*8) = o;
      }
    } else {
      const unsigned short* src = featB + (size_t)(m0 + row)*256 + cb;
#pragma unroll
      for (int i = 0; i < 4; i++)
        *(u16x8*)(B0 + row*264 + cb + i*8) = *(const u16x8*)(src + i*8);
    }
  }
  __syncthreads();

  // ---- geometry ----
  constexpr int NCH = 64 / CS;
  if (tid < NCH*3){
    int ch = tid / 3, c = tid - ch*3;
    float s = 0.f;
    for (int r = 0; r < CS; r++) s += P3[ch*CS + r][c];
    Cg[ch][c] = s / (float)CS;
  }
  __syncthreads();
  if (tid < 64){
    int ch = (CS == 16) ? (tid >> 4) : 0;
    float x = P3[tid][0] - Cg[ch][0];
    float y = P3[tid][1] - Cg[ch][1];
    float z = P3[tid][2] - Cg[ch][2];
    Gg[tid][0] = x; Gg[tid][1] = y; Gg[tid][2] = z;
    Gg[tid][3] = sqrtf(x*x + y*y + z*z);
  }
  __syncthreads();

  // ---- H1 = relu(G @ w1a + b1a) -> B1 ----
  {
    const int c = tid & 255;
    const int r0 = (tid >> 8) * 32;
    const float wa0 = w1a[c], wa1 = w1a[256+c], wa2 = w1a[512+c], wa3 = w1a[768+c];
    const float ba  = b1a[c];
    for (int r = r0; r < r0 + 32; r++){
      float v1 = ba + Gg[r][0]*wa0 + Gg[r][1]*wa1 + Gg[r][2]*wa2 + Gg[r][3]*wa3;
      B1[r*264 + c] = f2b(fmaxf(v1, 0.f));
    }
  }
  __syncthreads();
  // h_pos = fc + H1 @ m1w2 + b -> B2
  {
    f32x4 acc[4][2] = {};
    wg_gemm_reg(m1w2T, B1, tid, acc);
    wg_epi(acc, B2, B0, m1b2, tid);
  }
  // ---- H2 = relu(G @ w1b + b1b) -> B1 ----  (avg branch == 0 exactly)
  {
    const int c = tid & 255;
    const int r0 = (tid >> 8) * 32;
    const float wb0 = w1b[768+c], wb1 = w1b[1024+c], wb2 = w1b[1280+c];
    const float bb  = b1b[c];
    for (int r = r0; r < r0 + 32; r++){
      float v2 = bb + Gg[r][0]*wb0 + Gg[r][1]*wb1 + Gg[r][2]*wb2;
      B1[r*264 + c] = f2b(fmaxf(v2, 0.f));
    }
  }
  __syncthreads();
  // h_geo = fc + H2 @ m2w2 + b -> B3
  {
    f32x4 acc[4][2] = {};
    wg_gemm_reg(m2w2T, B1, tid, acc);
    wg_epi(acc, B3, B0, m2b2, tid);
  }
  // q = h_geo @ wq(/16) -> B0 (fc dead) ; k = h_geo @ wk -> B1
  {
    f32x4 acc[4][2] = {};
    wg_gemm_reg(wqT, B3, tid, acc);
    wg_epi(acc, B0, nullptr, nullptr, tid);
  }
  {
    f32x4 acc[4][2] = {};
    wg_gemm_reg(wkT, B3, tid, acc);
    wg_epi(acc, B1, nullptr, nullptr, tid);
  }

  // ---- S = q k^T -> Sb (B3; h_geo dead) ----
  if (CS == 64){
    const int tr = wave & 3, tc0 = wave >> 2;   // tiles (tr, tc0) and (tr, tc0+2)
    f32x4 sacc[2] = {};
    const int qrow = tr*16 + lrow;
#pragma unroll
    for (int kk = 0; kk < 8; kk++){
      bf16x8 aq = *(const bf16x8*)(B0 + qrow*264 + kk*32 + lq*8);
#pragma unroll
      for (int c = 0; c < 2; c++){
        int brow = (tc0 + c*2)*16 + lrow;
        bf16x8 bk = *(const bf16x8*)(B1 + brow*264 + kk*32 + lq*8);
        sacc[c] = __builtin_amdgcn_mfma_f32_16x16x32_bf16(aq, bk, sacc[c], 0, 0, 0);
      }
    }
#pragma unroll
    for (int c = 0; c < 2; c++)
#pragma unroll
      for (int r = 0; r < 4; r++)
        Sb[(tr*16 + lq*4 + r)*SS + (tc0 + c*2)*16 + lrow] = sacc[c][r];
  } else {
    if (wave < 4){
      f32x4 sacc = {};
      const int qrow = wave*16 + lrow;
#pragma unroll
      for (int kk = 0; kk < 8; kk++){
        bf16x8 aq = *(const bf16x8*)(B0 + qrow*264 + kk*32 + lq*8);
        bf16x8 bk = *(const bf16x8*)(B1 + qrow*264 + kk*32 + lq*8);
        sacc = __builtin_amdgcn_mfma_f32_16x16x32_bf16(aq, bk, sacc, 0, 0, 0);
      }
#pragma unroll
      for (int r = 0; r < 4; r++)
        Sb[(wave*16 + lq*4 + r)*SS + lrow] = sacc[r];
    }
  }
  __syncthreads();

  // ---- softmax -> Pb (bf16) ----
  if (tid < 64){
    float mx = -3.0e38f;
    for (int j = 0; j < CS; j++) mx = fmaxf(mx, Sb[tid*SS + j]);
    float sum = 0.f;
    for (int j = 0; j < CS; j++){
      float e = __expf(Sb[tid*SS + j] - mx);
      Sb[tid*SS + j] = e; sum += e;
    }
    float inv = 1.0f / sum;
    for (int j = 0; j < CS; j++) Pb[tid*PS + j] = f2b(Sb[tid*SS + j] * inv);
    if (CS == 16){
      for (int j = 16; j < 32; j++) Pb[tid*PS + j] = 0;
    }
  }
  __syncthreads();

  // ---- v = h_pos @ wv -> VT (transposed, over B0; q dead, k-head clobbered)
  {
    f32x4 acc[4][2] = {};
    wg_gemm_reg(wvT, B2, tid, acc);
    wg_epi_vt(acc, VT, tid);
  }

  // ---- O = P @ V -> B1 ----
  {
    f32x4 oacc[4][2] = {};
    const int dbase = wave * 32;
    if (CS == 64){
#pragma unroll
      for (int kk = 0; kk < 2; kk++){
        bf16x8 ap[4];
#pragma unroll
        for (int mt = 0; mt < 4; mt++)
          ap[mt] = *(const bf16x8*)(Pb + (mt*16 + lrow)*PS + kk*32 + lq*8);
#pragma unroll
        for (int nt = 0; nt < 2; nt++){
          const int d = dbase + nt*16 + lrow;
          bf16x8 bv = *(const bf16x8*)(VT + d*72 + kk*32 + lq*8);
#pragma unroll
          for (int mt = 0; mt < 4; mt++)
            oacc[mt][nt] = __builtin_amdgcn_mfma_f32_16x16x32_bf16(ap[mt], bv, oacc[mt][nt], 0, 0, 0);
        }
      }
    } else {
#pragma unroll
      for (int mt = 0; mt < 4; mt++){
        bf16x8 ap = *(const bf16x8*)(Pb + (mt*16 + lrow)*PS + lq*8);
#pragma unroll
        for (int nt = 0; nt < 2; nt++){
          const int d = dbase + nt*16 + lrow;
          bf16x8 bv = *(const bf16x8*)(VT + d*72 + mt*16 + (lq & 1)*8);
          oacc[mt][nt] = __builtin_amdgcn_mfma_f32_16x16x32_bf16(ap, bv, oacc[mt][nt], 0, 0, 0);
        }
      }
    }
    __syncthreads();   // all VT reads done before O overwrites B1 (VT spill)
#pragma unroll
    for (int mt = 0; mt < 4; mt++){
#pragma unroll
      for (int nt = 0; nt < 2; nt++){
#pragma unroll
        for (int r = 0; r < 4; r++){
          int row = mt*16 + lq*4 + r;
          int col = dbase + nt*16 + lrow;
          B1[row*264 + col] = f2b(oacc[mt][nt][r]);
        }
      }
    }
  }
  __syncthreads();

  // ---- y = O @ wo -> B0 ; then LN(y + bo + h_pos) -> out ----
  {
    f32x4 acc[4][2] = {};
    wg_gemm_reg(woT, B1, tid, acc);
    wg_epi(acc, B0, nullptr, nullptr, tid);
  }
  {
    const int row = tid >> 3, part = tid & 7;
    const size_t gr = (size_t)(m0 + row) * 256;
    float sm = 0.f, sq = 0.f;
#pragma unroll
    for (int i = 0; i < 4; i++){
      int col = part*32 + i*8;
      u16x8 v  = *(const u16x8*)(B0 + row*264 + col);
      u16x8 rr = *(const u16x8*)(B2 + row*264 + col);
      u16x8 w;
#pragma unroll
      for (int j = 0; j < 8; j++){
        float y = b2f(v[j]) + bo[col + j] + b2f(rr[j]);
        sm += y; sq += y*y;
        w[j] = f2b(y);
      }
      *(u16x8*)(B0 + row*264 + col) = w;
    }
    sred[row][part] = sm; s2red[row][part] = sq;
    __syncthreads();
    if (tid < 64){
      float s = 0.f, q2 = 0.f;
#pragma unroll
      for (int p = 0; p < 8; p++){ s += sred[tid][p]; q2 += s2red[tid][p]; }
      float mu = s * (1.0f/256.0f);
      float var = q2 * (1.0f/256.0f) - mu*mu;
      mub[tid] = mu;
      rsb[tid] = rsqrtf(var + 1e-5f);
    }
    __syncthreads();
    const float mu = mub[row], rs = rsb[row];
#pragma unroll
    for (int i = 0; i < 4; i++){
      int col = part*32 + i*8;
      u16x8 v = *(const u16x8*)(B0 + row*264 + col);
      u16x8 o;
#pragma unroll
      for (int j = 0; j < 8; j++)
        o[j] = f2b((b2f(v[j]) - mu)*rs*lgam[col + j] + lbet[col + j]);
      *(u16x8*)(out + gr + col) = o;
    }
  }
}

// ---------------------------------------------------------------------------
// Output: pos_ds gather + KNN max-pool.
// ---------------------------------------------------------------------------
__global__ __launch_bounds__(256) void out_k(
    const unsigned short* __restrict__ F2,
    const float* __restrict__ pos,
    const int* __restrict__ fps,
    const int* __restrict__ knn,
    float* __restrict__ outp)
{
  const int p = blockIdx.x;
  const int b = p >> 11;
  const int t = threadIdx.x;
  const int* kn = knn + (size_t)p * 16;
  const int c = t * 2;
  float m1 = -3.0e38f, m2 = -3.0e38f;
  for (int j = 0; j < 16; j++){
    int idx = kn[j];
    size_t row = ((size_t)b * 8192 + idx) * 512;
    u16x2 v = *(const u16x2*)(F2 + row + c);
    m1 = fmaxf(m1, b2f(v.x));
    m2 = fmaxf(m2, b2f(v.y));
  }
  float* of = outp + 49152 + (size_t)p * 512 + c;
  float2 o; o.x = m1; o.y = m2;
  *(float2*)of = o;
  if (t < 3){
    int fi = fps[p];
    outp[(size_t)p*3 + t] = pos[((size_t)b*8192 + fi)*3 + t];
  }
}

// ---------------------------------------------------------------------------
extern "C" void kernel_launch(void* const* d_in, const int* in_sizes, int n_in,
                              void* d_out, int out_size, void* d_ws, size_t ws_size,
                              hipStream_t stream)
{
  (void)in_sizes; (void)n_in; (void)out_size; (void)ws_size;

  const float* pos  = (const float*)d_in[0];
  const float* feat = (const float*)d_in[1];
  const int*   fps  = (const int*)d_in[2];
  const int*   knn  = (const int*)d_in[3];
  const float* m1w1 = (const float*)d_in[6];
  const float* m1b1 = (const float*)d_in[7];
  const float* m1w2 = (const float*)d_in[8];
  const float* m1b2 = (const float*)d_in[9];
  const float* m2w1 = (const float*)d_in[10];
  const float* m2b1 = (const float*)d_in[11];
  const float* m2w2 = (const float*)d_in[12];
  const float* m2b2 = (const float*)d_in[13];
  const float* wq   = (const float*)d_in[14];
  const float* wk   = (const float*)d_in[15];
  const float* wv   = (const float*)d_in[16];
  const float* wo   = (const float*)d_in[17];
  const float* bo   = (const float*)d_in[18];
  const float* lng  = (const float*)d_in[19];
  const float* lnb  = (const float*)d_in[20];
  const float* tdw  = (const float*)d_in[21];
  const float* tdb  = (const float*)d_in[22];
  const float* bng  = (const float*)d_in[23];
  const float* bnb  = (const float*)d_in[24];
  const float* bnm  = (const float*)d_in[25];
  const float* bnv  = (const float*)d_in[26];

  char* ws = (char*)d_ws;
  unsigned short* wT = (unsigned short*)ws;
  float* bns = (float*)(ws + 1835008);
  float* bnt = (float*)(ws + 1837056);
  const size_t SLOT = 33554432;
  unsigned short* A  = (unsigned short*)(ws + 2097152);
  unsigned short* Bs = (unsigned short*)(ws + 2097152 + SLOT);
  unsigned short* E  = (unsigned short*)(ws + 2097152 + 2*SLOT);

  auto wtm = [&](int mat, int i){ return wT + (size_t)mat*131072 + (size_t)i*65536; };
  unsigned short* tdT = wT + 786432;

  prep_k<<<3586, 256, 0, stream>>>(m1w2, m2w2, wq, wk, wv, wo, tdw, tdb, bng, bnb, bnm, bnv,
                                   wT, bns, bnt);

  block_k<16, true><<<1024, 512, 0, stream>>>(
      pos, feat, nullptr,
      m1w1, m1b1, m2w1, m2b1,
      wtm(0,0), m1b2, wtm(1,0), m2b2,
      wtm(2,0), wtm(3,0), wtm(4,0), wtm(5,0),
      bo, lng, lnb, A);

  block_k<64, false><<<1024, 512, 0, stream>>>(
      pos, nullptr, A,
      m1w1 + 1024, m1b1 + 256, m2w1 + 1536, m2b1 + 256,
      wtm(0,1), m1b2 + 256, wtm(1,1), m2b2 + 256,
      wtm(2,1), wtm(3,1), wtm(4,1), wtm(5,1),
      bo + 256, lng + 256, lnb + 256, Bs);

  gemm_k<<<dim3(512,4), 256, 0, stream>>>(Bs, tdT, E, nullptr, nullptr, bns, bnt, 512);

  out_k<<<16384, 256, 0, stream>>>(E, pos, fps, knn, (float*)d_out);
}